// Round 9
// baseline (52.522 us; speedup 1.0000x reference)
//
#include <hip/hip_runtime.h>
#include <hip/hip_bf16.h>

#define B_ 8
#define T_ 2048
#define D_ 256
#define S_ 2048

// Kernel 1: cos[b,t] for t in [0,T-2]. One wave per 8 consecutive rows with
// register row-reuse: 9 row-loads per 8 cos values; nsq of each row reduced
// once and carried (bit-identical math to the r8 per-pair version).
__global__ __launch_bounds__(256) void k_dotcos(const float* __restrict__ fr,
                                                float* __restrict__ cosg){
  int lane = threadIdx.x & 63;
  int w = threadIdx.x >> 6;
  long p0 = ((long)blockIdx.x * 4 + w) * 8;   // first row of this wave's chunk
  const float4* f4 = (const float4*)fr;
  float4 a = f4[p0 * 64 + lane];
  float na = a.x*a.x + a.y*a.y + a.z*a.z + a.w*a.w;
  #pragma unroll
  for (int m = 32; m >= 1; m >>= 1) na += __shfl_xor(na, m, 64);
  int rmax = (p0 + 8 <= (long)B_ * T_ - 1) ? 8 : 7;   // avoid OOB load on final chunk
  for (int r = 1; r <= rmax; ++r){
    long p = p0 + r;
    float4 c = f4[p * 64 + lane];
    float nc = c.x*c.x + c.y*c.y + c.z*c.z + c.w*c.w;
    float dt = a.x*c.x + a.y*c.y + a.z*c.z + a.w*c.w;
    #pragma unroll
    for (int m = 32; m >= 1; m >>= 1){
      nc += __shfl_xor(nc, m, 64);
      dt += __shfl_xor(dt, m, 64);
    }
    int t = (int)((p - 1) & (T_ - 1));
    if (lane == 0 && t != T_ - 1)
      cosg[p - 1] = dt / fmaxf(sqrtf(na) * sqrtf(nc), 1e-6f);
    a = c; na = nc;
  }
}

// Kernel 2 (fused boundary+colsum+pool): each block recomputes its batch's
// boundary chain from cosg (op-order bit-identical to the r8 k_boundary),
// then pools 16 s values (4 per wave). bc monotone => only t with
// bc[t] in [cc-1, cc+1] contribute > 4.2e-9.
__global__ __launch_bounds__(256) void k_fused(const float* __restrict__ fr,
                                               const float* __restrict__ cosg,
                                               float* __restrict__ out){
  __shared__ float sd[T_];     // cos -> d -> (after scan) bc
  __shared__ float sb[T_];     // b values
  __shared__ float smin[4], smax[4], swv[4], snum;
  int tid = threadIdx.x;
  int lane = tid & 63, w = tid >> 6;
  int b = blockIdx.y;
  int s0 = blockIdx.x * 16;
  const float* cG = cosg + b * T_;
  for (int t = tid; t < T_ - 1; t += 256) sd[t] = cG[t];
  __syncthreads();
  float mn = 1e30f, mx = -1e30f;
  for (int t = tid; t < T_ - 1; t += 256){ float v = sd[t]; mn = fminf(mn, v); mx = fmaxf(mx, v); }
  #pragma unroll
  for (int m = 32; m >= 1; m >>= 1){
    mn = fminf(mn, __shfl_xor(mn, m, 64));
    mx = fmaxf(mx, __shfl_xor(mx, m, 64));
  }
  if (lane == 0){ smin[w] = mn; smax[w] = mx; }
  __syncthreads();
  mn = fminf(fminf(smin[0], smin[1]), fminf(smin[2], smin[3]));
  mx = fmaxf(fmaxf(smax[0], smax[1]), fmaxf(smax[2], smax[3]));
  float inv = 1.0f / (mx - mn);
  for (int t = tid; t < T_ - 1; t += 256)
    sd[t] = 1.0f - (sd[t] - mn) * inv;
  __syncthreads();
  for (int t = tid; t < T_; t += 256){
    float v;
    if (t == 0) v = 1.0f;
    else {
      int i = t - 1;                          // index into d (length T-1)
      if (i < 2 || i > T_ - 4) v = 0.0f;      // p2[:, :2] = 0, p2[:, -2:] = 0
      else {
        float d0 = sd[i];
        float p2 = fminf(fmaxf(d0 - sd[i + 2], 0.0f), fmaxf(d0 - sd[i - 2], 0.0f));
        v = tanhf(1e7f * p2);
      }
    }
    sb[t] = v;
  }
  __syncthreads();
  // scan sb -> bc (into sd; d values are dead now). Same form as r8.
  float loc[8]; float s = 0.0f;
  #pragma unroll
  for (int j = 0; j < 8; ++j){ s += sb[8 * tid + j]; loc[j] = s; }
  float v = s;
  #pragma unroll
  for (int off = 1; off < 64; off <<= 1){
    float n = __shfl_up(v, (unsigned)off, 64);
    if (lane >= off) v += n;
  }
  if (lane == 63) swv[w] = v;
  __syncthreads();
  float wpre = 0.0f;
  for (int i = 0; i < w; ++i) wpre += swv[i];
  float excl = wpre + v - s;
  #pragma unroll
  for (int j = 0; j < 8; ++j) sd[8 * tid + j] = excl + loc[j];
  if (tid == 255) snum = excl + s;
  __syncthreads();
  float numfr = snum;
  // pool: wave w owns s = s0 + 4w + k, k=0..3; lanes hold float4 of D.
  const float4* f4 = (const float4*)(fr + (size_t)b * T_ * D_);
  for (int k = 0; k < 4; ++k){
    int sidx = s0 + w * 4 + k;
    float4 acc = {0.0f, 0.0f, 0.0f, 0.0f};
    if ((float)(sidx + 1) <= numfr){
      float cc = (float)(sidx + 1);
      float lov = cc - 1.0f, hiv = cc + 1.0f;
      int lo = 0, hi = T_;
      while (lo < hi){ int mid = (lo + hi) >> 1; if (sd[mid] < lov) lo = mid + 1; else hi = mid; }
      float scol = 0.0f;
      for (int t = lo; t < T_ && sd[t] <= hiv; ++t)
        scol += 1.0f - tanhf(10.0f * fabsf(cc - sd[t]));
      for (int t = lo; t < T_ && sd[t] <= hiv; ++t){
        float u = tanhf(10.0f * fabsf(cc - sd[t]));
        float m = (1.0f - u) / (scol + u);
        float4 f = f4[(size_t)t * 64 + lane];
        acc.x += m * f.x; acc.y += m * f.y; acc.z += m * f.z; acc.w += m * f.w;
      }
    }
    ((float4*)out)[((size_t)b * S_ + sidx) * 64 + lane] = acc;
  }
}

extern "C" void kernel_launch(void* const* d_in, const int* in_sizes, int n_in,
                              void* d_out, int out_size, void* d_ws, size_t ws_size,
                              hipStream_t stream) {
  const float* frames = (const float*)d_in[0];
  float* cosg = (float*)d_ws;            // B*T floats
  float* out = (float*)d_out;

  k_dotcos<<<B_ * T_ / 32, 256, 0, stream>>>(frames, cosg);
  k_fused<<<dim3(S_ / 16, B_), 256, 0, stream>>>(frames, cosg, out);
}

// Round 10
// 35.216 us; speedup vs baseline: 1.4914x; 1.4914x over previous
//
#include <hip/hip_runtime.h>
#include <hip/hip_bf16.h>

#define B_ 8
#define T_ 2048
#define D_ 256
#define S_ 2048

// Kernel 1: cos[b,t] = <f[t],f[t+1]> / max(|f[t]||f[t+1]|, 1e-6), t in [0,T-2].
// One wave per row t; loads rows t and t+1 as float4/lane; 3 f32 wave reductions.
__global__ __launch_bounds__(256) void k_dotcos(const float* __restrict__ fr,
                                                float* __restrict__ cosg){
  int lane = threadIdx.x & 63;
  int w = threadIdx.x >> 6;
  int p = blockIdx.x * 4 + w;                 // p = b*T + t
  int t = p & (T_ - 1);
  const float4* f4 = (const float4*)fr;
  float4 a = f4[(size_t)p * 64 + lane];
  float na = a.x*a.x + a.y*a.y + a.z*a.z + a.w*a.w;
  float nc = 0.0f, dt = 0.0f;
  if (t < T_ - 1){
    float4 c = f4[(size_t)(p + 1) * 64 + lane];
    nc = c.x*c.x + c.y*c.y + c.z*c.z + c.w*c.w;
    dt = a.x*c.x + a.y*c.y + a.z*c.z + a.w*c.w;
  }
  #pragma unroll
  for (int m = 32; m >= 1; m >>= 1){
    na += __shfl_xor(na, m, 64);
    nc += __shfl_xor(nc, m, 64);
    dt += __shfl_xor(dt, m, 64);
  }
  if (lane == 0 && t < T_ - 1)
    cosg[p] = dt / fmaxf(sqrtf(na) * sqrtf(nc), 1e-6f);
}

// Kernel 2 (fused boundary+colsum+pool): each block recomputes its batch's
// boundary chain from cosg (op-order bit-identical to r8's k_boundary), then
// each WAVE pools one s. Window [t: bc[t] in [cc-1,cc+1]] processed
// lane-parallel: prefix predicate via ballot, scol via wave reduce, fma pass
// via shfl-broadcast m with independent float4 loads.
__global__ __launch_bounds__(256) void k_fused(const float* __restrict__ fr,
                                               const float* __restrict__ cosg,
                                               float* __restrict__ out){
  __shared__ float sd[T_];     // cos -> d -> (after scan) bc
  __shared__ float sb[T_];     // b values
  __shared__ float smin[4], smax[4], swv[4], snum;
  int tid = threadIdx.x;
  int lane = tid & 63, w = tid >> 6;
  int b = blockIdx.y;
  int s = blockIdx.x * 4 + w;
  const float* cG = cosg + b * T_;
  for (int t = tid; t < T_ - 1; t += 256) sd[t] = cG[t];
  __syncthreads();
  float mn = 1e30f, mx = -1e30f;
  for (int t = tid; t < T_ - 1; t += 256){ float v = sd[t]; mn = fminf(mn, v); mx = fmaxf(mx, v); }
  #pragma unroll
  for (int m = 32; m >= 1; m >>= 1){
    mn = fminf(mn, __shfl_xor(mn, m, 64));
    mx = fmaxf(mx, __shfl_xor(mx, m, 64));
  }
  if (lane == 0){ smin[w] = mn; smax[w] = mx; }
  __syncthreads();
  mn = fminf(fminf(smin[0], smin[1]), fminf(smin[2], smin[3]));
  mx = fmaxf(fmaxf(smax[0], smax[1]), fmaxf(smax[2], smax[3]));
  float inv = 1.0f / (mx - mn);
  for (int t = tid; t < T_ - 1; t += 256)
    sd[t] = 1.0f - (sd[t] - mn) * inv;
  __syncthreads();
  for (int t = tid; t < T_; t += 256){
    float v;
    if (t == 0) v = 1.0f;
    else {
      int i = t - 1;                          // index into d (length T-1)
      if (i < 2 || i > T_ - 4) v = 0.0f;      // p2[:, :2] = 0, p2[:, -2:] = 0
      else {
        float d0 = sd[i];
        float p2 = fminf(fmaxf(d0 - sd[i + 2], 0.0f), fmaxf(d0 - sd[i - 2], 0.0f));
        v = tanhf(1e7f * p2);
      }
    }
    sb[t] = v;
  }
  __syncthreads();
  // scan sb -> bc (into sd; d values are dead now). Same form as r8.
  float loc[8]; float sum8 = 0.0f;
  #pragma unroll
  for (int j = 0; j < 8; ++j){ sum8 += sb[8 * tid + j]; loc[j] = sum8; }
  float v = sum8;
  #pragma unroll
  for (int off = 1; off < 64; off <<= 1){
    float n = __shfl_up(v, (unsigned)off, 64);
    if (lane >= off) v += n;
  }
  if (lane == 63) swv[w] = v;
  __syncthreads();
  float wpre = 0.0f;
  for (int i = 0; i < w; ++i) wpre += swv[i];
  float excl = wpre + v - sum8;
  #pragma unroll
  for (int j = 0; j < 8; ++j) sd[8 * tid + j] = excl + loc[j];
  if (tid == 255) snum = excl + sum8;
  __syncthreads();
  float numfr = snum;
  // pool: this wave owns s; lanes hold float4 of D.
  float4 acc = {0.0f, 0.0f, 0.0f, 0.0f};
  if ((float)(s + 1) <= numfr){
    float cc = (float)(s + 1);
    float lov = cc - 1.0f, hiv = cc + 1.0f;
    int lo = 0, hi = T_;
    while (lo < hi){ int mid = (lo + hi) >> 1; if (sd[mid] < lov) lo = mid + 1; else hi = mid; }
    // phase 1: scol, lane-parallel over the window (prefix predicate: bc monotone)
    float scol = 0.0f;
    for (int base = lo; base < T_; base += 64){
      int t = base + lane;
      bool in = (t < T_) && (sd[t] <= hiv);
      float res = 0.0f;
      if (in) res = 1.0f - tanhf(10.0f * fabsf(cc - sd[t]));
      float r = res;
      #pragma unroll
      for (int m = 32; m >= 1; m >>= 1) r += __shfl_xor(r, m, 64);
      scol += r;
      if (__popcll(__ballot(in)) < 64) break;
    }
    // phase 2: acc += m_t * frames[t], m broadcast via shfl, loads independent
    const float4* f4 = (const float4*)(fr + (size_t)b * T_ * D_);
    for (int base = lo; base < T_; base += 64){
      int t = base + lane;
      bool in = (t < T_) && (sd[t] <= hiv);
      float mval = 0.0f;
      if (in){
        float u = tanhf(10.0f * fabsf(cc - sd[t]));
        mval = (1.0f - u) / (scol + u);
      }
      int cnt = __popcll(__ballot(in));
      for (int j = 0; j < cnt; ++j){
        float mj = __shfl(mval, j, 64);
        float4 f = f4[(size_t)(base + j) * 64 + lane];
        acc.x += mj * f.x; acc.y += mj * f.y; acc.z += mj * f.z; acc.w += mj * f.w;
      }
      if (cnt < 64) break;
    }
  }
  ((float4*)out)[((size_t)b * S_ + s) * 64 + lane] = acc;
}

extern "C" void kernel_launch(void* const* d_in, const int* in_sizes, int n_in,
                              void* d_out, int out_size, void* d_ws, size_t ws_size,
                              hipStream_t stream) {
  const float* frames = (const float*)d_in[0];
  float* cosg = (float*)d_ws;            // B*T floats
  float* out = (float*)d_out;

  k_dotcos<<<B_ * T_ / 4, 256, 0, stream>>>(frames, cosg);
  k_fused<<<dim3(S_ / 4, B_), 256, 0, stream>>>(frames, cosg, out);
}